// Round 1
// baseline (183.901 us; speedup 1.0000x reference)
//
#include <hip/hip_runtime.h>
#include <math.h>

#define N_ANCHORS 2048
#define THRESH 0.3f
#define OVERLAP 0.5f
#define NBC 32

#define TRI(k, w) ((k) * ((k) + 1) / 2 + (w))   // triangular unit index

// =============== single fused kernel: decode+compact+rank+NMS+scatter ===============
// 32 blocks (one per batch*class), 512 threads. Everything LDS-resident; no workspace.
#define BLOCK 512
#define OFF_CSC   0
#define OFF_CBX   8208
#define OFF_CID   24592
#define OFF_SBOX  0
#define OFF_SSC   16896
#define OFF_SID   25088
#define POOL_SZ   29184

__global__ __launch_bounds__(BLOCK) void det_mono(
    const float* __restrict__ loc, const float* __restrict__ cls,
    const float* __restrict__ defs, float* __restrict__ out)
{
#pragma clang fp contract(off)
    const int tid  = threadIdx.x;
    const int lane = tid & 63;
    const int wid  = tid >> 6;
    const int bc   = blockIdx.x;
    const int b    = bc >> 2;
    const int c    = bc & 3;

    __shared__ __align__(16) unsigned char pool[POOL_SZ];
    __shared__ __align__(16) unsigned long long suprowT[8 * 512];
    __shared__ unsigned long long keptg[32];
    __shared__ unsigned long long s_deadw[8];
    __shared__ int s_wsum[8], s_woff[8], s_V;

    float*          csc  = (float*)(pool + OFF_CSC);
    float2*         cbx  = (float2*)(pool + OFF_CBX);
    unsigned short* cid  = (unsigned short*)(pool + OFF_CID);
    float2*         sbox = (float2*)(pool + OFF_SBOX);
    float*          ssc  = (float*)(pool + OFF_SSC);
    unsigned short* sid  = (unsigned short*)(pool + OFF_SID);

    float* const outb = out + (size_t)bc * N_ANCHORS * 3;
    {
        float4 z4 = make_float4(0.f, 0.f, 0.f, 0.f);
        float4* ob4 = (float4*)outb;
        for (int i = tid; i < (N_ANCHORS * 3) / 4; i += BLOCK) ob4[i] = z4;
    }
    if (tid < 32) keptg[tid] = 0ull;

    // ---- decode + softmax (4 anchors / thread) ----
    const int base = tid * 4;
    float c20[20], l8v[8], d8v[8];
    {
        const float4* cp4 = (const float4*)(cls + ((size_t)b * N_ANCHORS + base) * 5);
#pragma unroll
        for (int q = 0; q < 5; ++q) ((float4*)c20)[q] = cp4[q];
        const float4* lp4 = (const float4*)(loc + ((size_t)b * N_ANCHORS + base) * 2);
        ((float4*)l8v)[0] = lp4[0]; ((float4*)l8v)[1] = lp4[1];
        const float4* dp4 = (const float4*)(defs + (size_t)base * 2);
        ((float4*)d8v)[0] = dp4[0]; ((float4*)d8v)[1] = dp4[1];
    }
    float sc4[4], bs4[4], be4[4];
    int vmask = 0, cnt = 0;
#pragma unroll
    for (int k = 0; k < 4; ++k) {
        float x0 = c20[5*k+0], x1 = c20[5*k+1], x2 = c20[5*k+2],
              x3 = c20[5*k+3], x4 = c20[5*k+4];
        float m  = fmaxf(fmaxf(fmaxf(fmaxf(x0, x1), x2), x3), x4);
        float e0 = expf(x0 - m), e1 = expf(x1 - m), e2 = expf(x2 - m),
              e3 = expf(x3 - m), e4 = expf(x4 - m);
        float sum = e0 + e1 + e2 + e3 + e4;
        float ec  = (c == 0) ? e1 : (c == 1) ? e2 : (c == 2) ? e3 : e4;
        float score = ec / sum;
        float l0 = l8v[2*k], l1 = l8v[2*k+1];
        float d0 = d8v[2*k], d1 = d8v[2*k+1];
        float cc = d0 + l0 * d1;
        float w  = d1 * expf(l1);
        sc4[k] = score;
        bs4[k] = cc - 0.5f * w;
        be4[k] = cc + 0.5f * w;
        if (score > THRESH) { vmask |= (1 << k); cnt++; }
    }

    // ---- compact (block prefix sum) ----
    int inc = cnt;
    for (int d = 1; d < 64; d <<= 1) {
        int v = __shfl_up(inc, d);
        if (lane >= d) inc += v;
    }
    if (lane == 63) s_wsum[wid] = inc;
    __syncthreads();
    if (tid == 0) {
        int o = 0;
        for (int w = 0; w < 8; ++w) { s_woff[w] = o; o += s_wsum[w]; }
        s_V = o;
    }
    __syncthreads();
    {
        int off = s_woff[wid] + (inc - cnt);
#pragma unroll
        for (int k = 0; k < 4; ++k) {
            if (vmask & (1 << k)) {
                csc[off] = sc4[k];
                cbx[off] = make_float2(bs4[k], be4[k]);
                cid[off] = (unsigned short)(base + k);
                off++;
            }
        }
    }
    __syncthreads();
    const int V = s_V;
    const int SCend = ((V + 511) >> 9) << 9;
    if (tid < 4) csc[V + tid] = -INFINITY;
    __syncthreads();

    // ---- counting rank (stable sort by score desc, anchor-order tie-break) ----
#define RANKCMP(sv, ib, off2, mref, rref)                                   \
    rref += ((sv) > (mref) || ((sv) == (mref) && (ib) + (off2) < pcmp)) ? 1 : 0;
    int rr[4]; float2 rb[4]; float rs[4]; int ridv[4]; int nown = 0;
    if (V <= 512) {
        if (tid < 256) {
            int   p0 = tid, p1 = tid + 256;
            bool  a0 = p0 < V, a1 = p1 < V;
            float m0 = a0 ? csc[p0] : INFINITY;
            float m1 = a1 ? csc[p1] : INFINITY;
            int   r0 = 0, r1 = 0;
            const float4* cs4 = (const float4*)csc;
            const int n4 = (V + 3) >> 2;
            for (int i4 = 0; i4 < n4; ++i4) {
                float4 s4 = cs4[i4];
                int ib = i4 << 2;
                { int pcmp = p0;
                  RANKCMP(s4.x, ib, 0, m0, r0) RANKCMP(s4.y, ib, 1, m0, r0)
                  RANKCMP(s4.z, ib, 2, m0, r0) RANKCMP(s4.w, ib, 3, m0, r0) }
                { int pcmp = p1;
                  RANKCMP(s4.x, ib, 0, m1, r1) RANKCMP(s4.y, ib, 1, m1, r1)
                  RANKCMP(s4.z, ib, 2, m1, r1) RANKCMP(s4.w, ib, 3, m1, r1) }
            }
            if (a0) { rr[nown] = r0; rb[nown] = cbx[p0]; rs[nown] = m0; ridv[nown] = cid[p0]; nown++; }
            if (a1) { rr[nown] = r1; rb[nown] = cbx[p1]; rs[nown] = m1; ridv[nown] = cid[p1]; nown++; }
        }
    } else {
        for (int p = tid; p < V; p += BLOCK) {
            float s = csc[p];
            int r = 0;
            const float4* cs4 = (const float4*)csc;
            const int n4 = (V + 3) >> 2;
            for (int i4 = 0; i4 < n4; ++i4) {
                float4 s4 = cs4[i4];
                int ib = i4 << 2;
                int pcmp = p;
                RANKCMP(s4.x, ib, 0, s, r) RANKCMP(s4.y, ib, 1, s, r)
                RANKCMP(s4.z, ib, 2, s, r) RANKCMP(s4.w, ib, 3, s, r)
            }
            rr[nown] = r; rb[nown] = cbx[p]; rs[nown] = s; ridv[nown] = cid[p]; nown++;
        }
    }
#undef RANKCMP
    __syncthreads();      // all reads of csc/cbx/cid done (registers) before overwrite
    for (int q = 0; q < nown; ++q) {
        sbox[rr[q]] = rb[q];
        ssc[rr[q]]  = rs[q];
        sid[rr[q]]  = (unsigned short)ridv[q];
    }
    for (int i = V + tid; i < SCend; i += BLOCK)
        sbox[i] = make_float2(1e30f, 1e30f);
    __syncthreads();

    // ---- streaming 512-chunk NMS: build triangular suppression matrix in LDS,
    //      wave-0 bit-parallel greedy fixpoint (exactly reference's sequential greedy) ----
    for (int s0 = 0; s0 < V; s0 += 512) {
        const int scn = (V - s0 < 512) ? (V - s0) : 512;
        const int i   = tid;
        float2 my = sbox[s0 + i];
        float  ml = my.y - my.x;

        // dead-from-earlier-chunks: IoU vs kept boxes of earlier words
        bool dead = false;
        const int ew_n = s0 >> 6;
        for (int ew = 0; ew < ew_n; ++ew) {
            unsigned long long kw = keptg[ew];
            if (kw) {
                const float4* sb4 = (const float4*)(sbox + (ew << 6));
#pragma unroll
                for (int jj = 0; jj < 32; ++jj) {
                    float4 bp = sb4[jj];
                    float in0 = fmaxf(fminf(my.y, bp.y) - fmaxf(my.x, bp.x), 0.0f);
                    float un0 = (bp.y - bp.x) + ml - in0;
                    float io0 = in0 / fmaxf(un0, 1e-12f);
                    float in1 = fmaxf(fminf(my.y, bp.w) - fmaxf(my.x, bp.z), 0.0f);
                    float un1 = (bp.w - bp.z) + ml - in1;
                    float io1 = in1 / fmaxf(un1, 1e-12f);
                    unsigned long long bits = kw >> (2 * jj);
                    dead |= (io0 > OVERLAP) && ((bits & 1ull) != 0ull);
                    dead |= (io1 > OVERLAP) && ((bits & 2ull) != 0ull);
                }
            }
        }
        {
            unsigned long long db = __ballot(dead && (i < scn));
            if (lane == 0) s_deadw[wid] = db;
        }

        // in-chunk triangular matrix: 36 words round-robin over 8 waves
        {
            int t = 0;
#pragma unroll
            for (int k = 0; k < 8; ++k) {
#pragma unroll
                for (int w = 0; w <= k; ++w, ++t) {
                    if ((t & 7) == wid) {
                        const int u = (k << 6) + lane;
                        float2 ub = sbox[s0 + u];
                        float  ul = ub.y - ub.x;
                        const float4* sb4 = (const float4*)(sbox + s0 + (w << 6));
                        unsigned long long word = 0ull;
                        if (w == k) {
#pragma unroll
                            for (int jj = 0; jj < 32; ++jj) {
                                float4 bp = sb4[jj];
                                float in0 = fmaxf(fminf(ub.y, bp.y) - fmaxf(ub.x, bp.x), 0.0f);
                                float un0 = (bp.y - bp.x) + ul - in0;
                                float io0 = in0 / fmaxf(un0, 1e-12f);
                                float in1 = fmaxf(fminf(ub.y, bp.w) - fmaxf(ub.x, bp.z), 0.0f);
                                float un1 = (bp.w - bp.z) + ul - in1;
                                float io1 = in1 / fmaxf(un1, 1e-12f);
                                if (io0 > OVERLAP && 2 * jj     < lane) word |= (1ull << (2 * jj));
                                if (io1 > OVERLAP && 2 * jj + 1 < lane) word |= (1ull << (2 * jj + 1));
                            }
                        } else {
#pragma unroll
                            for (int jj = 0; jj < 32; ++jj) {
                                float4 bp = sb4[jj];
                                float in0 = fmaxf(fminf(ub.y, bp.y) - fmaxf(ub.x, bp.x), 0.0f);
                                float un0 = (bp.y - bp.x) + ul - in0;
                                float io0 = in0 / fmaxf(un0, 1e-12f);
                                float in1 = fmaxf(fminf(ub.y, bp.w) - fmaxf(ub.x, bp.z), 0.0f);
                                float un1 = (bp.w - bp.z) + ul - in1;
                                float io1 = in1 / fmaxf(un1, 1e-12f);
                                if (io0 > OVERLAP) word |= (1ull << (2 * jj));
                                if (io1 > OVERLAP) word |= (1ull << (2 * jj + 1));
                            }
                        }
                        suprowT[(w << 9) + u] = word;
                    }
                }
            }
        }
        __syncthreads();

        if (wid == 0) {
            unsigned long long row[36];
#pragma unroll
            for (int k = 0; k < 8; ++k)
#pragma unroll
                for (int w = 0; w <= k; ++w)
                    row[TRI(k, w)] = suprowT[(w << 9) + (k << 6) + lane];
            unsigned long long sdead[8];
#pragma unroll
            for (int w = 0; w < 8; ++w) sdead[w] = s_deadw[w];

            unsigned long long kv[8];
#pragma unroll
            for (int w = 0; w < 8; ++w) {
                kv[w] = 0ull;
                if ((w << 6) < scn) {
                    bool dl = ((sdead[w] >> lane) & 1ull) != 0ull;
#pragma unroll
                    for (int w2 = 0; w2 < w; ++w2)
                        dl |= (row[TRI(w, w2)] & kv[w2]) != 0ull;
                    const unsigned long long rself = row[TRI(w, w)];
                    int rem = scn - (w << 6);
                    unsigned long long valid = (rem >= 64) ? ~0ull : ((1ull << rem) - 1ull);
                    unsigned long long cand = valid & ~__ballot(dl);
                    unsigned long long kw = 0ull;
                    while (cand) {                 // in-word greedy levels
                        unsigned long long suppw = __ballot((rself & cand) != 0ull);
                        unsigned long long nk = cand & ~suppw;
                        if (!nk) nk = cand & (~cand + 1ull);   // acyclic: unreachable
                        kw |= nk;
                        unsigned long long ddw = __ballot((rself & nk) != 0ull);
                        cand &= ~(nk | ddw);
                    }
                    kv[w] = kw;
                }
            }
            if (lane == 0) {
#pragma unroll
                for (int w = 0; w < 8; ++w) keptg[(s0 >> 6) + w] |= kv[w];
            }
        }
        __syncthreads();
    }

    // ---- scatter kept boxes (in-range filter) ----
    for (int r = tid; r < V; r += BLOCK) {
        if ((keptg[r >> 6] >> (r & 63)) & 1ull) {
            float2 bx = sbox[r];
            if (bx.x > -10.0f && bx.y < 10.0f) {
                int n = sid[r];
                float* o = outb + (size_t)n * 3;
                o[0] = bx.x;
                o[1] = bx.y;
                o[2] = ssc[r];
            }
        }
    }
}

extern "C" void kernel_launch(void* const* d_in, const int* in_sizes, int n_in,
                              void* d_out, int out_size, void* d_ws, size_t ws_size,
                              hipStream_t stream) {
    const float* loc  = (const float*)d_in[0];  // localizations (8,2048,2)
    const float* cls  = (const float*)d_in[1];  // classifications (8,2048,5)
    const float* defs = (const float*)d_in[2];  // localizations_default (2048,2)
    float* out = (float*)d_out;                 // (8,4,2048,3) fp32
    (void)d_ws; (void)ws_size;
    det_mono<<<NBC, BLOCK, 0, stream>>>(loc, cls, defs, out);
}

// Round 2
// 162.300 us; speedup vs baseline: 1.1331x; 1.1331x over previous
//
#include <hip/hip_runtime.h>
#include <math.h>

#define N_ANCHORS 2048
#define THRESH 0.3f
#define OVERLAP 0.5f
#define NBC 32
#define BLOCK 512

// =============== single fused kernel: decode+compact+rank+NMS+scatter ===============
// 32 blocks (one per batch*class), 512 threads. Everything LDS-resident; no workspace.
// Lean code footprint: all big loops ROLLED (round-1 post-mortem: fully-unrolled
// 36-word matrix => ~200KB code, I$-streaming at 1 block/CU was the 130us stall).

__global__ __launch_bounds__(BLOCK, 1) void det_mono(
    const float* __restrict__ loc, const float* __restrict__ cls,
    const float* __restrict__ defs, float* __restrict__ out)
{
#pragma clang fp contract(off)
    const int tid  = threadIdx.x;
    const int lane = tid & 63;
    const int wid  = tid >> 6;
    const int bc   = blockIdx.x;
    const int b    = bc >> 2;
    const int c    = bc & 3;

    // ---- non-aliased LDS regions (~76 KB) ----
    __shared__ __align__(16) float          csc[2052];      // compacted scores (+4 pad)
    __shared__ __align__(16) float2         cbx[2048];      // compacted boxes
    __shared__                unsigned short cid[2048];     // compacted anchor ids
    __shared__ __align__(16) float2         sbox[2048];     // sorted boxes
    __shared__                float          ssc[2048];     // sorted scores
    __shared__                unsigned short sid[2048];     // sorted anchor ids
    __shared__ __align__(16) unsigned long long mat[36 * 64]; // triangular IoU words
    __shared__ unsigned long long keptg[32];
    __shared__ unsigned long long s_kv[8];
    __shared__ unsigned long long s_deadw[8];
    __shared__ int s_wsum[8], s_woff[8], s_V;

    float* const outb = out + (size_t)bc * N_ANCHORS * 3;
    {
        float4 z4 = make_float4(0.f, 0.f, 0.f, 0.f);
        float4* ob4 = (float4*)outb;
#pragma unroll 1
        for (int i = tid; i < (N_ANCHORS * 3) / 4; i += BLOCK) ob4[i] = z4;
    }
    if (tid < 32) keptg[tid] = 0ull;

    // ---- decode + softmax (4 anchors / thread) ----
    const int base = tid * 4;
    float c20[20], l8v[8], d8v[8];
    {
        const float4* cp4 = (const float4*)(cls + ((size_t)b * N_ANCHORS + base) * 5);
#pragma unroll
        for (int q = 0; q < 5; ++q) ((float4*)c20)[q] = cp4[q];
        const float4* lp4 = (const float4*)(loc + ((size_t)b * N_ANCHORS + base) * 2);
        ((float4*)l8v)[0] = lp4[0]; ((float4*)l8v)[1] = lp4[1];
        const float4* dp4 = (const float4*)(defs + (size_t)base * 2);
        ((float4*)d8v)[0] = dp4[0]; ((float4*)d8v)[1] = dp4[1];
    }
    float sc4[4], bs4[4], be4[4];
    int vmask = 0, cnt = 0;
#pragma unroll
    for (int k = 0; k < 4; ++k) {
        float x0 = c20[5*k+0], x1 = c20[5*k+1], x2 = c20[5*k+2],
              x3 = c20[5*k+3], x4 = c20[5*k+4];
        float m  = fmaxf(fmaxf(fmaxf(fmaxf(x0, x1), x2), x3), x4);
        float e0 = expf(x0 - m), e1 = expf(x1 - m), e2 = expf(x2 - m),
              e3 = expf(x3 - m), e4 = expf(x4 - m);
        float sum = e0 + e1 + e2 + e3 + e4;
        float ec  = (c == 0) ? e1 : (c == 1) ? e2 : (c == 2) ? e3 : e4;
        float score = ec / sum;
        float l0 = l8v[2*k], l1 = l8v[2*k+1];
        float d0 = d8v[2*k], d1 = d8v[2*k+1];
        float cc = d0 + l0 * d1;
        float w  = d1 * expf(l1);
        sc4[k] = score;
        bs4[k] = cc - 0.5f * w;
        be4[k] = cc + 0.5f * w;
        if (score > THRESH) { vmask |= (1 << k); cnt++; }
    }

    // ---- compact (block prefix sum) ----
    int inc = cnt;
#pragma unroll
    for (int d = 1; d < 64; d <<= 1) {
        int v = __shfl_up(inc, d);
        if (lane >= d) inc += v;
    }
    if (lane == 63) s_wsum[wid] = inc;
    __syncthreads();
    if (tid == 0) {
        int o = 0;
        for (int w = 0; w < 8; ++w) { s_woff[w] = o; o += s_wsum[w]; }
        s_V = o;
    }
    __syncthreads();
    {
        int off = s_woff[wid] + (inc - cnt);
#pragma unroll
        for (int k = 0; k < 4; ++k) {
            if (vmask & (1 << k)) {
                csc[off] = sc4[k];
                cbx[off] = make_float2(bs4[k], be4[k]);
                cid[off] = (unsigned short)(base + k);
                off++;
            }
        }
    }
    __syncthreads();
    const int V = s_V;
    const int SCend = ((V + 511) >> 9) << 9;
    if (tid < 4) csc[V + tid] = -INFINITY;   // float4-scan padding (never outranks)
    __syncthreads();

    // ---- counting rank (stable: score desc, anchor-order tie-break), direct scatter ----
#pragma unroll 1
    for (int p = tid; p < V; p += BLOCK) {
        float s = csc[p];
        int r = 0;
        const float4* cs4 = (const float4*)csc;
        const int n4 = (V + 3) >> 2;
#pragma unroll 2
        for (int i4 = 0; i4 < n4; ++i4) {
            float4 s4 = cs4[i4];
            int ib = i4 << 2;
            r += (s4.x > s || (s4.x == s && ib     < p)) ? 1 : 0;
            r += (s4.y > s || (s4.y == s && ib + 1 < p)) ? 1 : 0;
            r += (s4.z > s || (s4.z == s && ib + 2 < p)) ? 1 : 0;
            r += (s4.w > s || (s4.w == s && ib + 3 < p)) ? 1 : 0;
        }
        sbox[r] = cbx[p];
        ssc[r]  = s;
        sid[r]  = cid[p];
    }
#pragma unroll 1
    for (int i = V + tid; i < SCend; i += BLOCK)
        sbox[i] = make_float2(1e30f, 1e30f);
    __syncthreads();

    // ---- streaming 512-chunk NMS ----
#pragma unroll 1
    for (int s0 = 0; s0 < V; s0 += 512) {
        const int scn = (V - s0 < 512) ? (V - s0) : 512;
        const int i   = tid;
        float2 my = sbox[s0 + i];
        float  ml = my.y - my.x;

        // dead-from-earlier-chunks: IoU vs kept boxes of earlier words (no-op for s0==0)
        bool dead = false;
        const int ew_n = s0 >> 6;
#pragma unroll 1
        for (int ew = 0; ew < ew_n; ++ew) {
            unsigned long long kw = keptg[ew];
            if (kw) {
                const float4* sb4 = (const float4*)(sbox + (ew << 6));
#pragma unroll 1
                for (int jj = 0; jj < 32; ++jj) {
                    float4 bp = sb4[jj];
                    float in0 = fmaxf(fminf(my.y, bp.y) - fmaxf(my.x, bp.x), 0.0f);
                    float un0 = (bp.y - bp.x) + ml - in0;
                    float io0 = in0 / fmaxf(un0, 1e-12f);
                    float in1 = fmaxf(fminf(my.y, bp.w) - fmaxf(my.x, bp.z), 0.0f);
                    float un1 = (bp.w - bp.z) + ml - in1;
                    float io1 = in1 / fmaxf(un1, 1e-12f);
                    unsigned long long bits = kw >> (2 * jj);
                    dead |= (io0 > OVERLAP) && ((bits & 1ull) != 0ull);
                    dead |= (io1 > OVERLAP) && ((bits & 2ull) != 0ull);
                }
            }
        }
        {
            unsigned long long db = __ballot(dead && (i < scn));
            if (lane == 0) s_deadw[wid] = db;
        }

        // in-chunk triangular matrix: 36 words round-robin over 8 waves, ONE rolled copy
        {
            int k = 0, w = wid;
            while (w > k) { w -= (k + 1); ++k; }
#pragma unroll 1
            for (int t = wid; t < 36; t += 8) {
                if ((k << 6) < scn) {
                    const int u = (k << 6) + lane;
                    const float2 ub = sbox[s0 + u];
                    const float  ul = ub.y - ub.x;
                    const float4* sb4 = (const float4*)(sbox + s0 + (w << 6));
                    unsigned long long word = 0ull;
#pragma unroll 4
                    for (int jj = 0; jj < 32; ++jj) {
                        float4 bp = sb4[jj];
                        float in0 = fmaxf(fminf(ub.y, bp.y) - fmaxf(ub.x, bp.x), 0.0f);
                        float un0 = (bp.y - bp.x) + ul - in0;
                        float io0 = in0 / fmaxf(un0, 1e-12f);
                        float in1 = fmaxf(fminf(ub.y, bp.w) - fmaxf(ub.x, bp.z), 0.0f);
                        float un1 = (bp.w - bp.z) + ul - in1;
                        float io1 = in1 / fmaxf(un1, 1e-12f);
                        if (io0 > OVERLAP) word |= (1ull << (2 * jj));
                        if (io1 > OVERLAP) word |= (1ull << (2 * jj + 1));
                    }
                    if (w == k) word &= (1ull << lane) - 1ull;     // diagonal: only j < u
                    { int rem = scn - (w << 6); if (rem < 64) word &= (1ull << rem) - 1ull; }
                    if (u >= scn) word = 0ull;
                    mat[((size_t)t << 6) + lane] = word;           // t == TRI(k,w)
                }
                w += 8;
                while (w > k) { w -= (k + 1); ++k; }
            }
        }
        __syncthreads();

        // wave-0 bit-parallel greedy fixpoint over this chunk (reads mat on demand)
        if (wid == 0) {
            const int W = (scn + 63) >> 6;
#pragma unroll 1
            for (int g = 0; g < W; ++g) {
                const int gbase = (g * (g + 1)) >> 1;
                unsigned long long dl_or = 0ull;
#pragma unroll 1
                for (int w2 = 0; w2 < g; ++w2)
                    dl_or |= mat[((size_t)(gbase + w2) << 6) + lane] & s_kv[w2];
                const unsigned long long rself = mat[((size_t)(gbase + g) << 6) + lane];
                bool dl = (dl_or != 0ull) || (((s_deadw[g] >> lane) & 1ull) != 0ull);
                int rem = scn - (g << 6);
                unsigned long long valid = (rem >= 64) ? ~0ull : ((1ull << rem) - 1ull);
                unsigned long long cand = valid & ~__ballot(dl);
                unsigned long long kw = 0ull;
                while (cand) {                     // in-word greedy levels
                    unsigned long long suppw = __ballot((rself & cand) != 0ull);
                    unsigned long long nk = cand & ~suppw;
                    if (!nk) nk = cand & (~cand + 1ull);   // acyclic: unreachable
                    kw |= nk;
                    unsigned long long ddw = __ballot((rself & nk) != 0ull);
                    cand &= ~(nk | ddw);
                }
                if (lane == 0) { s_kv[g] = kw; keptg[(s0 >> 6) + g] = kw; }
            }
        }
        __syncthreads();
    }

    // ---- scatter kept boxes (in-range filter) ----
#pragma unroll 1
    for (int r = tid; r < V; r += BLOCK) {
        if ((keptg[r >> 6] >> (r & 63)) & 1ull) {
            float2 bx = sbox[r];
            if (bx.x > -10.0f && bx.y < 10.0f) {
                int n = sid[r];
                float* o = outb + (size_t)n * 3;
                o[0] = bx.x;
                o[1] = bx.y;
                o[2] = ssc[r];
            }
        }
    }
}

extern "C" void kernel_launch(void* const* d_in, const int* in_sizes, int n_in,
                              void* d_out, int out_size, void* d_ws, size_t ws_size,
                              hipStream_t stream) {
    const float* loc  = (const float*)d_in[0];  // localizations (8,2048,2)
    const float* cls  = (const float*)d_in[1];  // classifications (8,2048,5)
    const float* defs = (const float*)d_in[2];  // localizations_default (2048,2)
    float* out = (float*)d_out;                 // (8,4,2048,3) fp32
    (void)d_ws; (void)ws_size;
    det_mono<<<NBC, BLOCK, 0, stream>>>(loc, cls, defs, out);
}

// Round 3
// 131.573 us; speedup vs baseline: 1.3977x; 1.2335x over previous
//
#include <hip/hip_runtime.h>
#include <math.h>

#define N_ANCHORS 2048
#define THRESH 0.3f
#define OVERLAP 0.5f
#define NBC 32
#define BLOCK 1024
#define NW 16

// =============== single fused kernel: decode+compact+rank+NMS+scatter ===============
// 32 blocks (one per batch*class), 1024 threads (16 waves: latency hiding).
// Everything LDS-resident; no workspace. IoU test uses exact mul-compare
// (inter > 0.5*union, 0.5x exact) instead of IEEE divide: ~2x fewer instrs
// on the dominant matrix phase.

__global__ __launch_bounds__(BLOCK, 1) void det_mono(
    const float* __restrict__ loc, const float* __restrict__ cls,
    const float* __restrict__ defs, float* __restrict__ out)
{
#pragma clang fp contract(off)
    const int tid  = threadIdx.x;
    const int lane = tid & 63;
    const int wid  = tid >> 6;
    const int bc   = blockIdx.x;
    const int b    = bc >> 2;
    const int c    = bc & 3;

    __shared__ __align__(16) float          csc[2052];      // compacted scores (+4 pad)
    __shared__ __align__(16) float2         cbx[2048];      // compacted boxes
    __shared__                unsigned short cid[2048];     // compacted anchor ids
    __shared__ __align__(16) float2         sbox[2048];     // sorted boxes
    __shared__                float          ssc[2048];     // sorted scores
    __shared__                unsigned short sid[2048];     // sorted anchor ids
    __shared__ __align__(16) unsigned long long mat[36 * 64]; // triangular IoU words
    __shared__ unsigned long long keptg[32];
    __shared__ unsigned long long s_kv[8];
    __shared__ unsigned long long s_deadw[8];
    __shared__ int s_wsum[NW], s_woff[NW], s_V;

    float* const outb = out + (size_t)bc * N_ANCHORS * 3;
    {
        float4 z4 = make_float4(0.f, 0.f, 0.f, 0.f);
        float4* ob4 = (float4*)outb;
#pragma unroll 1
        for (int i = tid; i < (N_ANCHORS * 3) / 4; i += BLOCK) ob4[i] = z4;
    }
    if (tid < 32) keptg[tid] = 0ull;

    // ---- decode + softmax (2 anchors / thread) ----
    const int base = tid * 2;
    float c10[10], l4v[4], d4v[4];
    {
        const float2* cp2 = (const float2*)(cls + ((size_t)b * N_ANCHORS + base) * 5);
#pragma unroll
        for (int q = 0; q < 5; ++q) ((float2*)c10)[q] = cp2[q];
        ((float4*)l4v)[0] = *(const float4*)(loc + ((size_t)b * N_ANCHORS + base) * 2);
        ((float4*)d4v)[0] = *(const float4*)(defs + (size_t)base * 2);
    }
    float sc2[2], bs2[2], be2[2];
    int vmask = 0, cnt = 0;
#pragma unroll
    for (int k = 0; k < 2; ++k) {
        float x0 = c10[5*k+0], x1 = c10[5*k+1], x2 = c10[5*k+2],
              x3 = c10[5*k+3], x4 = c10[5*k+4];
        float m  = fmaxf(fmaxf(fmaxf(fmaxf(x0, x1), x2), x3), x4);
        float e0 = expf(x0 - m), e1 = expf(x1 - m), e2 = expf(x2 - m),
              e3 = expf(x3 - m), e4 = expf(x4 - m);
        float sum = e0 + e1 + e2 + e3 + e4;
        float ec  = (c == 0) ? e1 : (c == 1) ? e2 : (c == 2) ? e3 : e4;
        float score = ec / sum;
        float l0 = l4v[2*k], l1 = l4v[2*k+1];
        float d0 = d4v[2*k], d1 = d4v[2*k+1];
        float cc = d0 + l0 * d1;
        float w  = d1 * expf(l1);
        sc2[k] = score;
        bs2[k] = cc - 0.5f * w;
        be2[k] = cc + 0.5f * w;
        if (score > THRESH) { vmask |= (1 << k); cnt++; }
    }

    // ---- compact (block prefix sum over 16 waves) ----
    int inc = cnt;
#pragma unroll
    for (int d = 1; d < 64; d <<= 1) {
        int v = __shfl_up(inc, d);
        if (lane >= d) inc += v;
    }
    if (lane == 63) s_wsum[wid] = inc;
    __syncthreads();
    if (tid == 0) {
        int o = 0;
        for (int w = 0; w < NW; ++w) { s_woff[w] = o; o += s_wsum[w]; }
        s_V = o;
    }
    __syncthreads();
    {
        int off = s_woff[wid] + (inc - cnt);
#pragma unroll
        for (int k = 0; k < 2; ++k) {
            if (vmask & (1 << k)) {
                csc[off] = sc2[k];
                cbx[off] = make_float2(bs2[k], be2[k]);
                cid[off] = (unsigned short)(base + k);
                off++;
            }
        }
    }
    __syncthreads();
    const int V = s_V;
    const int SCend = ((V + 511) >> 9) << 9;
    if (tid < 4) csc[V + tid] = -INFINITY;   // float4-scan padding (never outranks)
    __syncthreads();

    // ---- counting rank (stable: score desc, anchor-order tie-break), direct scatter ----
#pragma unroll 1
    for (int p = tid; p < V; p += BLOCK) {
        float s = csc[p];
        int r = 0;
        const float4* cs4 = (const float4*)csc;
        const int n4 = (V + 3) >> 2;
#pragma unroll 2
        for (int i4 = 0; i4 < n4; ++i4) {
            float4 s4 = cs4[i4];
            int ib = i4 << 2;
            r += (s4.x > s || (s4.x == s && ib     < p)) ? 1 : 0;
            r += (s4.y > s || (s4.y == s && ib + 1 < p)) ? 1 : 0;
            r += (s4.z > s || (s4.z == s && ib + 2 < p)) ? 1 : 0;
            r += (s4.w > s || (s4.w == s && ib + 3 < p)) ? 1 : 0;
        }
        sbox[r] = cbx[p];
        ssc[r]  = s;
        sid[r]  = cid[p];
    }
#pragma unroll 1
    for (int i = V + tid; i < SCend; i += BLOCK)
        sbox[i] = make_float2(1e30f, 1e30f);
    __syncthreads();

    // ---- streaming 512-chunk NMS ----
#pragma unroll 1
    for (int s0 = 0; s0 < V; s0 += 512) {
        const int scn = (V - s0 < 512) ? (V - s0) : 512;

        // dead-from-earlier-chunks (waves 0-7 only; no-op when s0==0)
        if (tid < 512) {
            const int i = tid;
            float2 my = sbox[s0 + i];
            float  ml = my.y - my.x;
            bool dead = false;
            const int ew_n = s0 >> 6;
#pragma unroll 1
            for (int ew = 0; ew < ew_n; ++ew) {
                unsigned long long kw = keptg[ew];
                if (kw) {
                    const float4* sb4 = (const float4*)(sbox + (ew << 6));
#pragma unroll 1
                    for (int jj = 0; jj < 32; ++jj) {
                        float4 bp = sb4[jj];
                        float in0 = fmaxf(fminf(my.y, bp.y) - fmaxf(my.x, bp.x), 0.0f);
                        float un0 = (bp.y - bp.x) + ml - in0;
                        float in1 = fmaxf(fminf(my.y, bp.w) - fmaxf(my.x, bp.z), 0.0f);
                        float un1 = (bp.w - bp.z) + ml - in1;
                        unsigned long long bits = kw >> (2 * jj);
                        dead |= (in0 > OVERLAP * fmaxf(un0, 1e-12f)) && ((bits & 1ull) != 0ull);
                        dead |= (in1 > OVERLAP * fmaxf(un1, 1e-12f)) && ((bits & 2ull) != 0ull);
                    }
                }
            }
            unsigned long long db = __ballot(dead && (i < scn));
            if (lane == 0) s_deadw[wid] = db;
        }

        // in-chunk triangular matrix: 36 words round-robin over 16 waves
        {
            int k = 0, w = wid;
            while (w > k) { w -= (k + 1); ++k; }
#pragma unroll 1
            for (int t = wid; t < 36; t += NW) {
                if ((k << 6) < scn) {
                    const int u = (k << 6) + lane;
                    const float2 ub = sbox[s0 + u];
                    const float  ul = ub.y - ub.x;
                    const float4* sb4 = (const float4*)(sbox + s0 + (w << 6));
                    unsigned long long word = 0ull;
#pragma unroll 4
                    for (int jj = 0; jj < 32; ++jj) {
                        float4 bp = sb4[jj];
                        float in0 = fmaxf(fminf(ub.y, bp.y) - fmaxf(ub.x, bp.x), 0.0f);
                        float un0 = (bp.y - bp.x) + ul - in0;
                        float in1 = fmaxf(fminf(ub.y, bp.w) - fmaxf(ub.x, bp.z), 0.0f);
                        float un1 = (bp.w - bp.z) + ul - in1;
                        if (in0 > OVERLAP * fmaxf(un0, 1e-12f)) word |= (1ull << (2 * jj));
                        if (in1 > OVERLAP * fmaxf(un1, 1e-12f)) word |= (1ull << (2 * jj + 1));
                    }
                    if (w == k) word &= (1ull << lane) - 1ull;     // diagonal: only j < u
                    { int rem = scn - (w << 6); if (rem < 64) word &= (1ull << rem) - 1ull; }
                    if (u >= scn) word = 0ull;
                    mat[((size_t)t << 6) + lane] = word;           // t == TRI(k,w)
                }
                w += NW;
                while (w > k) { w -= (k + 1); ++k; }
            }
        }
        __syncthreads();

        // wave-0 bit-parallel greedy fixpoint over this chunk
        if (wid == 0) {
            const int W = (scn + 63) >> 6;
#pragma unroll 1
            for (int g = 0; g < W; ++g) {
                const int gbase = (g * (g + 1)) >> 1;
                unsigned long long dl_or = 0ull;
#pragma unroll 1
                for (int w2 = 0; w2 < g; ++w2)
                    dl_or |= mat[((size_t)(gbase + w2) << 6) + lane] & s_kv[w2];
                const unsigned long long rself = mat[((size_t)(gbase + g) << 6) + lane];
                bool dl = (dl_or != 0ull) || (((s_deadw[g] >> lane) & 1ull) != 0ull);
                int rem = scn - (g << 6);
                unsigned long long valid = (rem >= 64) ? ~0ull : ((1ull << rem) - 1ull);
                unsigned long long cand = valid & ~__ballot(dl);
                unsigned long long kw = 0ull;
                while (cand) {                     // in-word greedy levels
                    unsigned long long suppw = __ballot((rself & cand) != 0ull);
                    unsigned long long nk = cand & ~suppw;
                    if (!nk) nk = cand & (~cand + 1ull);   // acyclic: unreachable
                    kw |= nk;
                    unsigned long long ddw = __ballot((rself & nk) != 0ull);
                    cand &= ~(nk | ddw);
                }
                if (lane == 0) { s_kv[g] = kw; keptg[(s0 >> 6) + g] = kw; }
            }
        }
        __syncthreads();
    }

    // ---- scatter kept boxes (in-range filter) ----
#pragma unroll 1
    for (int r = tid; r < V; r += BLOCK) {
        if ((keptg[r >> 6] >> (r & 63)) & 1ull) {
            float2 bx = sbox[r];
            if (bx.x > -10.0f && bx.y < 10.0f) {
                int n = sid[r];
                float* o = outb + (size_t)n * 3;
                o[0] = bx.x;
                o[1] = bx.y;
                o[2] = ssc[r];
            }
        }
    }
}

extern "C" void kernel_launch(void* const* d_in, const int* in_sizes, int n_in,
                              void* d_out, int out_size, void* d_ws, size_t ws_size,
                              hipStream_t stream) {
    const float* loc  = (const float*)d_in[0];  // localizations (8,2048,2)
    const float* cls  = (const float*)d_in[1];  // classifications (8,2048,5)
    const float* defs = (const float*)d_in[2];  // localizations_default (2048,2)
    float* out = (float*)d_out;                 // (8,4,2048,3) fp32
    (void)d_ws; (void)ws_size;
    det_mono<<<NBC, BLOCK, 0, stream>>>(loc, cls, defs, out);
}

// Round 4
// 91.627 us; speedup vs baseline: 2.0071x; 1.4360x over previous
//
#include <hip/hip_runtime.h>
#include <math.h>

#define N_ANCHORS 2048
#define THRESH 0.3f
#define OVERLAP 0.5f
#define NBC 32
#define BLOCK 1024
#define NW 16

// ====== single fused kernel: decode+compact+rank+frontier-NMS+scatter ======
// 32 blocks (one per batch*class), 1024 threads (16 waves).
// Round-4: O(V^2) triangular IoU matrix replaced by word-sequential frontier:
// a box can only be suppressed by a KEPT box (exact greedy property), so the
// cross-word test scans the compacted kept list (K << V) instead of all pairs.
// In-word 64x64 diagonal built via transposed __ballot (1 instr per 64 bits).

__global__ __launch_bounds__(BLOCK, 1) void det_mono(
    const float* __restrict__ loc, const float* __restrict__ cls,
    const float* __restrict__ defs, float* __restrict__ out)
{
#pragma clang fp contract(off)
    const int tid  = threadIdx.x;
    const int lane = tid & 63;
    const int wid  = tid >> 6;
    const int bc   = blockIdx.x;
    const int b    = bc >> 2;
    const int c    = bc & 3;

    __shared__ __align__(16) float          csc[2052];      // compacted scores (+4 pad)
    __shared__ __align__(16) float2         cbx[2048];      // compacted boxes
    __shared__                unsigned short cid[2048];     // compacted anchor ids
    __shared__ __align__(16) float2         sbox[2048];     // sorted boxes (64-padded)
    __shared__                float          ssc[2048];     // sorted scores
    __shared__                unsigned short sid[2048];     // sorted anchor ids
    __shared__ __align__(16) float4         kbx[2048];      // kept list (s,e,len,_)
    __shared__ unsigned long long diag[64];                 // in-word diagonal rows
    __shared__ unsigned long long deadp[NW];                // per-wave dead partials
    __shared__ unsigned long long keptg[32];                // kept bitmask per word
    __shared__ int s_rp[512];                               // rank partials (col-split)
    __shared__ int s_wsum[NW], s_woff[NW], s_V, s_K;

    float* const outb = out + (size_t)bc * N_ANCHORS * 3;
    {
        float4 z4 = make_float4(0.f, 0.f, 0.f, 0.f);
        float4* ob4 = (float4*)outb;
#pragma unroll 1
        for (int i = tid; i < (N_ANCHORS * 3) / 4; i += BLOCK) ob4[i] = z4;
    }
    if (tid < 32) keptg[tid] = 0ull;
    if (tid == 0) s_K = 0;

    // ---- decode + softmax (2 anchors / thread) ----
    const int base = tid * 2;
    float c10[10], l4v[4], d4v[4];
    {
        const float2* cp2 = (const float2*)(cls + ((size_t)b * N_ANCHORS + base) * 5);
#pragma unroll
        for (int q = 0; q < 5; ++q) ((float2*)c10)[q] = cp2[q];
        ((float4*)l4v)[0] = *(const float4*)(loc + ((size_t)b * N_ANCHORS + base) * 2);
        ((float4*)d4v)[0] = *(const float4*)(defs + (size_t)base * 2);
    }
    float sc2[2], bs2[2], be2[2];
    int vmask = 0, cnt = 0;
#pragma unroll
    for (int k = 0; k < 2; ++k) {
        float x0 = c10[5*k+0], x1 = c10[5*k+1], x2 = c10[5*k+2],
              x3 = c10[5*k+3], x4 = c10[5*k+4];
        float m  = fmaxf(fmaxf(fmaxf(fmaxf(x0, x1), x2), x3), x4);
        float e0 = expf(x0 - m), e1 = expf(x1 - m), e2 = expf(x2 - m),
              e3 = expf(x3 - m), e4 = expf(x4 - m);
        float sum = e0 + e1 + e2 + e3 + e4;
        float ec  = (c == 0) ? e1 : (c == 1) ? e2 : (c == 2) ? e3 : e4;
        float score = ec / sum;
        float l0 = l4v[2*k], l1 = l4v[2*k+1];
        float d0 = d4v[2*k], d1 = d4v[2*k+1];
        float cc = d0 + l0 * d1;
        float w  = d1 * expf(l1);
        sc2[k] = score;
        bs2[k] = cc - 0.5f * w;
        be2[k] = cc + 0.5f * w;
        if (score > THRESH) { vmask |= (1 << k); cnt++; }
    }

    // ---- compact (block prefix sum over 16 waves) ----
    int inc = cnt;
#pragma unroll
    for (int d = 1; d < 64; d <<= 1) {
        int v = __shfl_up(inc, d);
        if (lane >= d) inc += v;
    }
    if (lane == 63) s_wsum[wid] = inc;
    __syncthreads();
    if (tid == 0) {
        int o = 0;
        for (int w = 0; w < NW; ++w) { s_woff[w] = o; o += s_wsum[w]; }
        s_V = o;
    }
    __syncthreads();
    {
        int off = s_woff[wid] + (inc - cnt);
#pragma unroll
        for (int k = 0; k < 2; ++k) {
            if (vmask & (1 << k)) {
                csc[off] = sc2[k];
                cbx[off] = make_float2(bs2[k], be2[k]);
                cid[off] = (unsigned short)(base + k);
                off++;
            }
        }
    }
    __syncthreads();
    const int V = s_V;
    const int W = (V + 63) >> 6;
    const int SCend = W << 6;                 // 64-aligned padded extent
    if (tid < 4) csc[V + tid] = -INFINITY;    // float4-scan padding (never outranks)
    __syncthreads();

    // ---- counting rank (stable: score desc, anchor-order tie-break) ----
    {
        const float4* cs4 = (const float4*)csc;
        const int n4 = (V + 3) >> 2;
        if (V <= 512) {
            // column-split: tid<512 scans cols [0,h4), tid>=512 scans [h4,n4)
            const int p  = tid & 511;
            const int sg = tid >> 9;
            const int h4 = n4 >> 1;
            const int i40 = sg ? h4 : 0, i41 = sg ? n4 : h4;
            int r = 0; float s = 0.f;
            if (p < V) {
                s = csc[p];
#pragma unroll 2
                for (int i4 = i40; i4 < i41; ++i4) {
                    float4 s4 = cs4[i4];
                    int ib = i4 << 2;
                    r += (s4.x > s || (s4.x == s && ib     < p)) ? 1 : 0;
                    r += (s4.y > s || (s4.y == s && ib + 1 < p)) ? 1 : 0;
                    r += (s4.z > s || (s4.z == s && ib + 2 < p)) ? 1 : 0;
                    r += (s4.w > s || (s4.w == s && ib + 3 < p)) ? 1 : 0;
                }
            }
            if (sg && p < V) s_rp[p] = r;
            __syncthreads();
            if (!sg && p < V) {
                r += s_rp[p];
                sbox[r] = cbx[p];
                ssc[r]  = s;
                sid[r]  = cid[p];
            }
        } else {
#pragma unroll 1
            for (int p = tid; p < V; p += BLOCK) {
                float s = csc[p];
                int r = 0;
#pragma unroll 2
                for (int i4 = 0; i4 < n4; ++i4) {
                    float4 s4 = cs4[i4];
                    int ib = i4 << 2;
                    r += (s4.x > s || (s4.x == s && ib     < p)) ? 1 : 0;
                    r += (s4.y > s || (s4.y == s && ib + 1 < p)) ? 1 : 0;
                    r += (s4.z > s || (s4.z == s && ib + 2 < p)) ? 1 : 0;
                    r += (s4.w > s || (s4.w == s && ib + 3 < p)) ? 1 : 0;
                }
                sbox[r] = cbx[p];
                ssc[r]  = s;
                sid[r]  = cid[p];
            }
        }
    }
#pragma unroll 1
    for (int i = V + tid; i < SCend; i += BLOCK)
        sbox[i] = make_float2(1e30f, 1e30f);   // sentinel: IoU vs anything = 0
    __syncthreads();

    // ---- frontier NMS: word-sequential, kept-only cross-word scan ----
#pragma unroll 1
    for (int g = 0; g < W; ++g) {
        const int u = (g << 6) + lane;
        const float2 cb = sbox[u];             // this lane's candidate (sentinel-padded)
        const float  cl = cb.y - cb.x;

        // cross-word dead test vs kept list, distributed over 16 waves
        const int K = s_K;
        bool dead = false;
#pragma unroll 1
        for (int i = wid; i < K; i += NW) {
            float4 kb = kbx[i];                // uniform (broadcast) LDS read
            float in = fmaxf(fminf(cb.y, kb.y) - fmaxf(cb.x, kb.x), 0.0f);
            float un = kb.z + cl - in;         // len_kept + len_cand - in
            dead |= (in > OVERLAP * fmaxf(un, 1e-12f));
        }
        {
            unsigned long long db = __ballot(dead);
            if (lane == 0) deadp[wid] = db;
        }

        // in-word diagonal rows via transposed ballot: wave w computes rows 4w..4w+3
#pragma unroll
        for (int q = 0; q < 4; ++q) {
            const int r = (wid << 2) + q;
            const float2 rb = sbox[(g << 6) + r];   // uniform read
            const float  rl = rb.y - rb.x;
            float in = fmaxf(fminf(rb.y, cb.y) - fmaxf(rb.x, cb.x), 0.0f);
            float un = cl + rl - in;                 // len_col + len_row - in
            bool sup = (in > OVERLAP * fmaxf(un, 1e-12f));
            unsigned long long bal = __ballot(sup);
            if (lane == 0) diag[r] = bal & ((1ull << r) - 1ull);   // only j < r
        }
        __syncthreads();

        // wave-0: reduce dead partials, in-word greedy fixpoint, append kept
        if (wid == 0) {
            unsigned long long dw = 0ull;
#pragma unroll
            for (int i = 0; i < NW; ++i) dw |= deadp[i];
            const unsigned long long rself = diag[lane];
            int rem = V - (g << 6);
            unsigned long long valid = (rem >= 64) ? ~0ull : ((1ull << rem) - 1ull);
            unsigned long long cand = valid & ~dw;
            unsigned long long kw = 0ull;
            while (cand) {                     // in-word greedy levels
                unsigned long long suppw = __ballot((rself & cand) != 0ull);
                unsigned long long nk = cand & ~suppw;
                if (!nk) nk = cand & (~cand + 1ull);   // acyclic: unreachable
                kw |= nk;
                unsigned long long ddw = __ballot((rself & nk) != 0ull);
                cand &= ~(nk | ddw);
            }
            if ((kw >> lane) & 1ull) {
                int pos = s_K + __popcll(kw & ((1ull << lane) - 1ull));
                kbx[pos] = make_float4(cb.x, cb.y, cl, 0.f);
            }
            if (lane == 0) { keptg[g] = kw; s_K += __popcll(kw); }
        }
        __syncthreads();
    }

    // ---- scatter kept boxes (in-range filter) ----
#pragma unroll 1
    for (int r = tid; r < V; r += BLOCK) {
        if ((keptg[r >> 6] >> (r & 63)) & 1ull) {
            float2 bx = sbox[r];
            if (bx.x > -10.0f && bx.y < 10.0f) {
                int n = sid[r];
                float* o = outb + (size_t)n * 3;
                o[0] = bx.x;
                o[1] = bx.y;
                o[2] = ssc[r];
            }
        }
    }
}

extern "C" void kernel_launch(void* const* d_in, const int* in_sizes, int n_in,
                              void* d_out, int out_size, void* d_ws, size_t ws_size,
                              hipStream_t stream) {
    const float* loc  = (const float*)d_in[0];  // localizations (8,2048,2)
    const float* cls  = (const float*)d_in[1];  // classifications (8,2048,5)
    const float* defs = (const float*)d_in[2];  // localizations_default (2048,2)
    float* out = (float*)d_out;                 // (8,4,2048,3) fp32
    (void)d_ws; (void)ws_size;
    det_mono<<<NBC, BLOCK, 0, stream>>>(loc, cls, defs, out);
}

// Round 5
// 77.870 us; speedup vs baseline: 2.3617x; 1.1767x over previous
//
#include <hip/hip_runtime.h>
#include <math.h>

#define N_ANCHORS 2048
#define THRESH 0.3f
#define OVERLAP 0.5f
#define NBC 32
#define BLOCK 1024
#define NW 16
#define BUCKET_BASE 32051   // __float_as_uint(0.3f) >> 15; scores in (0.3,1.0] -> idx in [0,461]

// ====== single fused kernel: decode+compact+bucket-rank+frontier-NMS+scatter ======
// 32 blocks (one per batch*class), 1024 threads (16 waves).
// Round-5: O(V^2) counting rank replaced by monotonic bit-bucket counting sort
// (462 buckets) + exact in-bucket comparator (avg ~6 members): same stable order,
// ~6x fewer rank instructions. Frontier NMS unchanged (validated round 4).

__global__ __launch_bounds__(BLOCK, 1) void det_mono(
    const float* __restrict__ loc, const float* __restrict__ cls,
    const float* __restrict__ defs, float* __restrict__ out)
{
#pragma clang fp contract(off)
    const int tid  = threadIdx.x;
    const int lane = tid & 63;
    const int wid  = tid >> 6;
    const int bc   = blockIdx.x;
    const int b    = bc >> 2;
    const int c    = bc & 3;

    __shared__ __align__(16) float          csc[2048];      // compacted scores
    __shared__ __align__(16) float2         cbx[2048];      // compacted boxes
    __shared__                unsigned short cid[2048];     // compacted anchor ids
    __shared__ __align__(16) float2         sbox[2048];     // sorted boxes (64-padded)
    __shared__                float          ssc[2048];     // sorted scores
    __shared__                unsigned short sid[2048];     // sorted anchor ids
    __shared__ __align__(16) float4         kbx[2048];      // kept list (s,e,len,_)
    __shared__                unsigned short blist[2048];   // bucket-grouped element ids
    __shared__ int s_hist[512];                             // bucket counts
    __shared__ int s_off[512];                              // bucket offsets (desc), then end-cursors
    __shared__ unsigned long long diag[64];                 // in-word diagonal rows
    __shared__ unsigned long long deadp[NW];                // per-wave dead partials
    __shared__ unsigned long long keptg[32];                // kept bitmask per word
    __shared__ int s_wsum[NW], s_woff[NW], s_V, s_K;

    float* const outb = out + (size_t)bc * N_ANCHORS * 3;
    {
        float4 z4 = make_float4(0.f, 0.f, 0.f, 0.f);
        float4* ob4 = (float4*)outb;
#pragma unroll 1
        for (int i = tid; i < (N_ANCHORS * 3) / 4; i += BLOCK) ob4[i] = z4;
    }
    if (tid < 32) keptg[tid] = 0ull;
    if (tid < 512) s_hist[tid] = 0;
    if (tid == 0) s_K = 0;

    // ---- decode + softmax (2 anchors / thread) ----
    const int base = tid * 2;
    float c10[10], l4v[4], d4v[4];
    {
        const float2* cp2 = (const float2*)(cls + ((size_t)b * N_ANCHORS + base) * 5);
#pragma unroll
        for (int q = 0; q < 5; ++q) ((float2*)c10)[q] = cp2[q];
        ((float4*)l4v)[0] = *(const float4*)(loc + ((size_t)b * N_ANCHORS + base) * 2);
        ((float4*)d4v)[0] = *(const float4*)(defs + (size_t)base * 2);
    }
    float sc2[2], bs2[2], be2[2];
    int vmask = 0;
#pragma unroll
    for (int k = 0; k < 2; ++k) {
        float x0 = c10[5*k+0], x1 = c10[5*k+1], x2 = c10[5*k+2],
              x3 = c10[5*k+3], x4 = c10[5*k+4];
        float m  = fmaxf(fmaxf(fmaxf(fmaxf(x0, x1), x2), x3), x4);
        float e0 = expf(x0 - m), e1 = expf(x1 - m), e2 = expf(x2 - m),
              e3 = expf(x3 - m), e4 = expf(x4 - m);
        float sum = e0 + e1 + e2 + e3 + e4;
        float ec  = (c == 0) ? e1 : (c == 1) ? e2 : (c == 2) ? e3 : e4;
        float score = ec / sum;
        float l0 = l4v[2*k], l1 = l4v[2*k+1];
        float d0 = d4v[2*k], d1 = d4v[2*k+1];
        float cc = d0 + l0 * d1;
        float w  = d1 * expf(l1);
        sc2[k] = score;
        bs2[k] = cc - 0.5f * w;
        be2[k] = cc + 0.5f * w;
        if (score > THRESH) vmask |= (1 << k);
    }

    // ---- compact (ballot-based block prefix over 16 waves; anchor-ascending order) ----
    const unsigned long long lmlt = (1ull << lane) - 1ull;
    unsigned long long b0 = __ballot(vmask & 1);
    unsigned long long b1 = __ballot(vmask & 2);
    int exc  = __popcll(b0 & lmlt) + __popcll(b1 & lmlt);
    if (lane == 0) s_wsum[wid] = __popcll(b0) + __popcll(b1);
    __syncthreads();
    if (tid == 0) {
        int o = 0;
        for (int w = 0; w < NW; ++w) { s_woff[w] = o; o += s_wsum[w]; }
        s_V = o;
    }
    __syncthreads();
    {
        int off = s_woff[wid] + exc;
#pragma unroll
        for (int k = 0; k < 2; ++k) {
            if (vmask & (1 << k)) {
                csc[off] = sc2[k];
                cbx[off] = make_float2(bs2[k], be2[k]);
                cid[off] = (unsigned short)(base + k);
                off++;
            }
        }
    }
    __syncthreads();
    const int V = s_V;
    const int W = (V + 63) >> 6;
    const int SCend = W << 6;                 // 64-aligned padded extent

    // ---- bucket rank: monotonic bit-buckets + exact in-bucket comparator ----
    // histogram
#pragma unroll 1
    for (int p = tid; p < V; p += BLOCK) {
        unsigned bkt = (__float_as_uint(csc[p]) >> 15) - BUCKET_BASE;
        atomicAdd(&s_hist[bkt], 1);
    }
    __syncthreads();
    // wave-0: descending exclusive scan (s_off[b] = #elems in buckets > b)
    if (wid == 0) {
        int running = 0;
#pragma unroll 1
        for (int ch = 0; ch < 8; ++ch) {
            int bidx = 511 - ((ch << 6) + lane);       // high buckets first
            int v = s_hist[bidx];
            int incv = v;
#pragma unroll
            for (int d = 1; d < 64; d <<= 1) {
                int t = __shfl_up(incv, d);
                if (lane >= d) incv += t;
            }
            s_off[bidx] = running + incv - v;          // exclusive
            running += __shfl(incv, 63);
        }
    }
    __syncthreads();
    // placement (arrival order; s_off becomes end-cursor)
#pragma unroll 1
    for (int p = tid; p < V; p += BLOCK) {
        unsigned bkt = (__float_as_uint(csc[p]) >> 15) - BUCKET_BASE;
        int slot = atomicAdd(&s_off[bkt], 1);
        blist[slot] = (unsigned short)p;
    }
    __syncthreads();
    // exact stable rank within bucket (score desc, anchor-order tie-break), scatter
#pragma unroll 1
    for (int p = tid; p < V; p += BLOCK) {
        float s = csc[p];
        unsigned bkt = (__float_as_uint(s) >> 15) - BUCKET_BASE;
        int end = s_off[bkt], cnt = s_hist[bkt];
        int r = end - cnt;                              // base: all higher buckets
#pragma unroll 1
        for (int t = end - cnt; t < end; ++t) {
            int e = blist[t];
            float s2 = csc[e];
            r += (s2 > s || (s2 == s && e < p)) ? 1 : 0;
        }
        sbox[r] = cbx[p];
        ssc[r]  = s;
        sid[r]  = cid[p];
    }
#pragma unroll 1
    for (int i = V + tid; i < SCend; i += BLOCK)
        sbox[i] = make_float2(1e30f, 1e30f);   // sentinel: IoU vs anything = 0
    __syncthreads();

    // ---- frontier NMS: word-sequential, kept-only cross-word scan ----
#pragma unroll 1
    for (int g = 0; g < W; ++g) {
        const int u = (g << 6) + lane;
        const float2 cb = sbox[u];             // this lane's candidate (sentinel-padded)
        const float  cl = cb.y - cb.x;

        // cross-word dead test vs kept list, distributed over 16 waves
        const int K = s_K;
        bool dead = false;
#pragma unroll 1
        for (int i = wid; i < K; i += NW) {
            float4 kb = kbx[i];                // uniform (broadcast) LDS read
            float in = fmaxf(fminf(cb.y, kb.y) - fmaxf(cb.x, kb.x), 0.0f);
            float un = kb.z + cl - in;         // len_kept + len_cand - in
            dead |= (in > OVERLAP * fmaxf(un, 1e-12f));
        }
        {
            unsigned long long db = __ballot(dead);
            if (lane == 0) deadp[wid] = db;
        }

        // in-word diagonal rows via transposed ballot: wave w computes rows 4w..4w+3
#pragma unroll
        for (int q = 0; q < 4; ++q) {
            const int r = (wid << 2) + q;
            const float2 rb = sbox[(g << 6) + r];   // uniform read
            const float  rl = rb.y - rb.x;
            float in = fmaxf(fminf(rb.y, cb.y) - fmaxf(rb.x, cb.x), 0.0f);
            float un = cl + rl - in;                 // len_col + len_row - in
            bool sup = (in > OVERLAP * fmaxf(un, 1e-12f));
            unsigned long long bal = __ballot(sup);
            if (lane == 0) diag[r] = bal & ((1ull << r) - 1ull);   // only j < r
        }
        __syncthreads();

        // wave-0: reduce dead partials, in-word greedy fixpoint, append kept
        if (wid == 0) {
            unsigned long long dw = 0ull;
#pragma unroll
            for (int i = 0; i < NW; ++i) dw |= deadp[i];
            const unsigned long long rself = diag[lane];
            int rem = V - (g << 6);
            unsigned long long valid = (rem >= 64) ? ~0ull : ((1ull << rem) - 1ull);
            unsigned long long cand = valid & ~dw;
            unsigned long long kw = 0ull;
            while (cand) {                     // in-word greedy levels
                unsigned long long suppw = __ballot((rself & cand) != 0ull);
                unsigned long long nk = cand & ~suppw;
                if (!nk) nk = cand & (~cand + 1ull);   // acyclic: unreachable
                kw |= nk;
                unsigned long long ddw = __ballot((rself & nk) != 0ull);
                cand &= ~(nk | ddw);
            }
            if ((kw >> lane) & 1ull) {
                int pos = s_K + __popcll(kw & ((1ull << lane) - 1ull));
                kbx[pos] = make_float4(cb.x, cb.y, cl, 0.f);
            }
            if (lane == 0) { keptg[g] = kw; s_K += __popcll(kw); }
        }
        __syncthreads();
    }

    // ---- scatter kept boxes (in-range filter) ----
#pragma unroll 1
    for (int r = tid; r < V; r += BLOCK) {
        if ((keptg[r >> 6] >> (r & 63)) & 1ull) {
            float2 bx = sbox[r];
            if (bx.x > -10.0f && bx.y < 10.0f) {
                int n = sid[r];
                float* o = outb + (size_t)n * 3;
                o[0] = bx.x;
                o[1] = bx.y;
                o[2] = ssc[r];
            }
        }
    }
}

extern "C" void kernel_launch(void* const* d_in, const int* in_sizes, int n_in,
                              void* d_out, int out_size, void* d_ws, size_t ws_size,
                              hipStream_t stream) {
    const float* loc  = (const float*)d_in[0];  // localizations (8,2048,2)
    const float* cls  = (const float*)d_in[1];  // classifications (8,2048,5)
    const float* defs = (const float*)d_in[2];  // localizations_default (2048,2)
    float* out = (float*)d_out;                 // (8,4,2048,3) fp32
    (void)d_ws; (void)ws_size;
    det_mono<<<NBC, BLOCK, 0, stream>>>(loc, cls, defs, out);
}